// Round 3
// baseline (431.303 us; speedup 1.0000x reference)
//
#include <hip/hip_runtime.h>
#include <hip/hip_bf16.h>
#include <cstdint>
#include <cstddef>

// ---------------------------------------------------------------------------
// DatastoreReaderLayer: S=256 B=4 D=512 N=32768, TEMP=0.5
// Math restructured:
//   q1 = (q @ Wq^T + bq) * D^-0.5                      [1024,512] fp32
//   Q2 = (q1 @ Wk) * (1/TEMP)  (bf16)   cq = (q1.bk)*(1/TEMP)
//   E[q,n] = exp(Q2[q,:].k_raw[n,:] + cq[q])  (no max-sub; logits ~N(0,1))
//   racc = E @ V_raw (fp32, split-N atomics), l = rowsum(E)
//   attn = (racc/l) @ Wv^T + bv
//   h = relu([attn|prev] @ Wg1^T + bg1); s = sigmoid(h.wg2 + bg2)
//   out = attn*s + prev*(1-s)        (row index qi = s*B+b == input layout!)
// WS BUDGET: needs ws_size >= 74,457,088 bytes (kfr 32MB, vt 32MB, rest ~9MB)
//
// R3 flash restructure:
//  - K pre-swizzled to MFMA-fragment order (prep_kfrag): each B-fragment is
//    one coalesced global_load_dwordx4 direct to registers -> no Ks LDS,
//    no K staging barriers. K streams from L2 (XCD remap keeps it resident).
//  - ONE raw barrier per sub: s_waitcnt lgkmcnt(0) + s_barrier +
//    sched_barrier(0). No vmcnt(0) drain -> K/V prefetch stays in flight
//    across barriers (the R2 structure drained vmcnt at every __syncthreads).
//  - logits accumulator split into 2 chains; PV(s-1) placed right after the
//    barrier so it covers the K-fragment L2 latency of sub s.
// ---------------------------------------------------------------------------

typedef unsigned short u16;
typedef u16    u16x8 __attribute__((ext_vector_type(8)));
typedef u16    u16x4 __attribute__((ext_vector_type(4)));
typedef __bf16 bf16x8 __attribute__((ext_vector_type(8)));
typedef float  f32x4 __attribute__((ext_vector_type(4)));

#define MFMA16(a, b, c) __builtin_amdgcn_mfma_f32_16x16x32_bf16( \
    __builtin_bit_cast(bf16x8, (a)), __builtin_bit_cast(bf16x8, (b)), (c), 0, 0, 0)

__device__ __forceinline__ u16 f2bf(float f) {  // RNE float->bf16
  unsigned u = __builtin_bit_cast(unsigned, f);
  u += 0x7fffu + ((u >> 16) & 1u);
  return (u16)(u >> 16);
}

// ---------- prep: dstore_k fp32 -> bf16 in MFMA-fragment order --------------
// Fragment (gsub, nh, ks): lane ln = quad*16+l15 holds
//   K[gsub*32 + nh*16 + l15][ks*32 + quad*8 + j]  (j=0..7)
// at kfr[gsub*16384 + (nh*16+ks)*512 + ln*8 + j].
__global__ __launch_bounds__(256) void prep_kfrag(const float* __restrict__ src,
                                                  u16* __restrict__ dst) {
  const int sub = blockIdx.x;  // 1024 subs of 32 rows
  const int t = threadIdx.x;
  const float* s0 = src + (size_t)sub * 32 * 512;
  u16* d0 = dst + (size_t)sub * 16384;
#pragma unroll
  for (int u = 0; u < 8; u++) {
    int ci = t + 256 * u;  // cell id 0..2047
    int nh = ci >> 10, ks = (ci >> 6) & 15, ln = ci & 63;
    int qd = ln >> 4, l15 = ln & 15;
    const float* sp = s0 + (size_t)(nh * 16 + l15) * 512 + ks * 32 + qd * 8;
    float4 a = *(const float4*)sp;
    float4 b = *(const float4*)(sp + 4);
    u16x8 o = {f2bf(a.x), f2bf(a.y), f2bf(a.z), f2bf(a.w),
               f2bf(b.x), f2bf(b.y), f2bf(b.z), f2bf(b.w)};
    *(u16x8*)(d0 + (size_t)ci * 8) = o;
  }
}

// --------------- prep: dstore_v -> bf16 transposed [512][32768] -------------
__global__ __launch_bounds__(256) void prep_vt(const float* __restrict__ v,
                                               u16* __restrict__ vt) {
  __shared__ u16 Lt[64 * 72];  // [d_local][n_local+pad]
  const int n0 = blockIdx.x * 64, d0 = blockIdx.y * 64;
  const int t = threadIdx.x;
  const int n = t >> 2, c4 = t & 3;
#pragma unroll
  for (int i = 0; i < 4; i++) {
    int col = (c4 + 4 * i) * 4;
    float4 x = *(const float4*)(v + (size_t)(n0 + n) * 512 + d0 + col);
    Lt[(col + 0) * 72 + n] = f2bf(x.x);
    Lt[(col + 1) * 72 + n] = f2bf(x.y);
    Lt[(col + 2) * 72 + n] = f2bf(x.z);
    Lt[(col + 3) * 72 + n] = f2bf(x.w);
  }
  __syncthreads();
#pragma unroll
  for (int u = 0; u < 2; u++) {
    int unit = t + 256 * u;  // 512 units: 64 d-rows x 8 units of 8 ushorts
    int d = unit >> 3, un = unit & 7;
    *(u16x8*)(vt + (size_t)(d0 + d) * 32768 + n0 + un * 8) =
        *(const u16x8*)&Lt[d * 72 + un * 8];
  }
}

// ---------------- small MFMA GEMM: C = act((A @ op(B) + bias)*alpha) --------
// A [M,K] fp32 row-major (CONCAT: A cols 0..511, A2 cols 512..1023, lda=512)
// TRANSB: B [N,K] (use B rows);  !TRANSB: B [K,N]
// ROWSCALE: A row r scaled by 1/lvec[r] during staging
template <bool TRANSB, bool CONCAT, bool RELU, bool OUTBF16, bool ROWSCALE>
__global__ __launch_bounds__(256, 2) void gemm64(
    const float* __restrict__ A, const float* __restrict__ A2,
    const float* __restrict__ B, const float* __restrict__ bias,
    const float* __restrict__ lvec, float alpha, void* __restrict__ Cv,
    int M, int N, int K) {
  __shared__ u16 As[64 * 72];
  __shared__ u16 Bs[64 * 72];  // [n_local][k_local]
  const int tid = threadIdx.x;
  const int w = tid >> 6, lane = tid & 63, quad = lane >> 4, l15 = lane & 15;
  const int m0 = blockIdx.y * 64, n0 = blockIdx.x * 64;
  const int arow = tid >> 2, ac4 = tid & 3;
  float rs = 1.0f;
  if (ROWSCALE) rs = 1.0f / lvec[m0 + arow];
  const f32x4 fzero = {0.f, 0.f, 0.f, 0.f};
  f32x4 acc[4];
#pragma unroll
  for (int i = 0; i < 4; i++) acc[i] = fzero;

  for (int k0 = 0; k0 < K; k0 += 64) {
    __syncthreads();
    {  // stage A tile (row-major [m][k], bf16)
      const float* src;
      if (CONCAT)
        src = (k0 < 512) ? (A + (size_t)(m0 + arow) * 512 + k0)
                         : (A2 + (size_t)(m0 + arow) * 512 + (k0 - 512));
      else
        src = A + (size_t)(m0 + arow) * K + k0;
#pragma unroll
      for (int i = 0; i < 4; i++) {
        int col = (ac4 + 4 * i) * 4;
        float4 x = *(const float4*)(src + col);
        if (ROWSCALE) { x.x *= rs; x.y *= rs; x.z *= rs; x.w *= rs; }
        u16x4 o = {f2bf(x.x), f2bf(x.y), f2bf(x.z), f2bf(x.w)};
        *(u16x4*)&As[arow * 72 + col] = o;
      }
    }
    if (TRANSB) {  // B [N,K]: rows are n -> same staging pattern
      const float* src = B + (size_t)(n0 + arow) * K + k0;
#pragma unroll
      for (int i = 0; i < 4; i++) {
        int col = (ac4 + 4 * i) * 4;
        float4 x = *(const float4*)(src + col);
        u16x4 o = {f2bf(x.x), f2bf(x.y), f2bf(x.z), f2bf(x.w)};
        *(u16x4*)&Bs[arow * 72 + col] = o;
      }
    } else {  // B [K,N]: transpose into Bs[n][k]
      const float* src = B + (size_t)(k0 + arow) * N + n0;
#pragma unroll
      for (int i = 0; i < 4; i++) {
        int col = (ac4 + 4 * i) * 4;
        float4 x = *(const float4*)(src + col);
        Bs[(col + 0) * 72 + arow] = f2bf(x.x);
        Bs[(col + 1) * 72 + arow] = f2bf(x.y);
        Bs[(col + 2) * 72 + arow] = f2bf(x.z);
        Bs[(col + 3) * 72 + arow] = f2bf(x.w);
      }
    }
    __syncthreads();
#pragma unroll
    for (int ks = 0; ks < 2; ks++) {
      u16x8 af = *(const u16x8*)&As[(w * 16 + l15) * 72 + ks * 32 + quad * 8];
#pragma unroll
      for (int nt = 0; nt < 4; nt++) {
        u16x8 bf = *(const u16x8*)&Bs[(nt * 16 + l15) * 72 + ks * 32 + quad * 8];
        acc[nt] = MFMA16(af, bf, acc[nt]);
      }
    }
  }
#pragma unroll
  for (int nt = 0; nt < 4; nt++) {
    int col = n0 + nt * 16 + l15;
    float b = bias ? bias[col] : 0.f;
#pragma unroll
    for (int i = 0; i < 4; i++) {
      int row = m0 + w * 16 + quad * 4 + i;
      float y = (acc[nt][i] + b) * alpha;
      if (RELU) y = fmaxf(y, 0.f);
      if (OUTBF16)
        ((u16*)Cv)[(size_t)row * N + col] = f2bf(y);
      else
        ((float*)Cv)[(size_t)row * N + col] = y;
    }
  }
}

// ----------------------------- cq = 2*(q1 . bk) -----------------------------
__global__ void cq_kernel(const float* __restrict__ q1,
                          const float* __restrict__ bk,
                          float* __restrict__ cq) {
  int r = blockIdx.x, lane = threadIdx.x;  // 64 threads = 1 wave
  float s = 0.f;
#pragma unroll
  for (int k = 0; k < 512; k += 64) s += q1[(size_t)r * 512 + k + lane] * bk[k + lane];
#pragma unroll
  for (int off = 32; off; off >>= 1) s += __shfl_down(s, off, 64);
  if (lane == 0) cq[r] = 2.0f * s;
}

// ------------------------------- flash kernel -------------------------------
// grid 256, 8 waves. XCD remap: x=bx&7 (XCD), j=bx>>3; ch=2x+(j&1), qt=j>>1.
// wave w: logits rows qg=w>>1 (16q) x n-half nh=w&1 (16n of 32);
//         PV: all 64q x cols [w*64, w*64+64).
// Per sub (ONE raw barrier, no vmcnt drain):
//   [lgkmcnt(0); s_barrier; sched_barrier]
//   issue 16 kf loads (sub)  -> ef reads + PV(sub-1) -> issue bv loads (sub)
//   -> logits(sub) (2 chains) -> exp -> Es[sub&1]
__global__ __launch_bounds__(512, 2) void flash(
    const u16* __restrict__ kfr,  // fragment-ordered K (see prep_kfrag)
    const u16* __restrict__ vt,   // [512][32768] bf16 (transposed V)
    const u16* __restrict__ q2,   // [1024][512] bf16 (scaled 2*(q1@Wk))
    const float* __restrict__ cq, // [1024]
    float* __restrict__ racc,     // [1024][512] fp32, pre-zeroed
    float* __restrict__ lacc) {   // [1024] fp32, pre-zeroed
  __shared__ u16 Es[2][64 * 40];  // double-buffered [q_local][n_local+pad]
  const int tid = threadIdx.x;
  const int w = tid >> 6, lane = tid & 63, quad = lane >> 4, l15 = lane & 15;
  const int x = blockIdx.x & 7, j = blockIdx.x >> 3;
  const int ch = 2 * x + (j & 1), qt = j >> 1;
  const int qbase = qt * 64;
  const int qg = w >> 1, nh = w & 1;
  const int colb = w * 64;

  // Q fragments: 16 x (16q x 32d) in registers (64 VGPRs)
  u16x8 qf[16];
  {
    const u16* qp = q2 + (size_t)(qbase + qg * 16 + l15) * 512 + quad * 8;
#pragma unroll
    for (int ks = 0; ks < 16; ks++) qf[ks] = *(const u16x8*)(qp + ks * 32);
  }
  float cq4[4];
#pragma unroll
  for (int i = 0; i < 4; i++) cq4[i] = cq[qbase + qg * 16 + quad * 4 + i];
  float lp[4] = {0.f, 0.f, 0.f, 0.f};
  const f32x4 fzero = {0.f, 0.f, 0.f, 0.f};
  f32x4 acc[4][4];
#pragma unroll
  for (int a = 0; a < 4; a++)
#pragma unroll
    for (int b = 0; b < 4; b++) acc[a][b] = fzero;

  // K-fragment base for this wave: frag(sub, ks) at
  //   kfr[((ch*64+sub)*2 + nh)*16*512 + ks*512 + lane*8]
  const u16* kp0 = kfr + (((size_t)(ch * 64) * 2 + nh) * 16) * 512 + lane * 8;
  // V base per d-tile ct: vt[(colb+ct*16+l15)*32768 + ch*2048 + sub*32 + quad*8]
  const u16* vp0 = vt + (size_t)(colb + l15) * 32768 + ch * 2048 + quad * 8;

  u16x8 kf[16];  // this sub's K fragments (64 VGPRs)
  u16x8 bv[4];   // this sub's V fragments (consumed next sub)

#define LOAD_KF(SUB)                                                     \
  {                                                                      \
    const u16* kps = kp0 + (size_t)(SUB) * 16384;                        \
    _Pragma("unroll") for (int ks = 0; ks < 16; ks++)                    \
        kf[ks] = *(const u16x8*)(kps + ks * 512);                        \
  }
#define LOAD_V(SUB)                                                      \
  {                                                                      \
    _Pragma("unroll") for (int ct = 0; ct < 4; ct++)                     \
        bv[ct] = *(const u16x8*)(vp0 + (size_t)ct * (16 * 32768) +       \
                                 (SUB) * 32);                            \
  }
#define LOGITS(SV)                                                       \
  {                                                                      \
    f32x4 s0_ = fzero, s1_ = fzero;                                      \
    _Pragma("unroll") for (int ks = 0; ks < 16; ks += 2) {               \
      s0_ = MFMA16(qf[ks], kf[ks], s0_);                                 \
      s1_ = MFMA16(qf[ks + 1], kf[ks + 1], s1_);                         \
    }                                                                    \
    SV = s0_ + s1_;                                                      \
  }
#define PV_STEP(ER)                                                      \
  {                                                                      \
    u16x8 ef[4];                                                         \
    _Pragma("unroll") for (int q2i = 0; q2i < 4; q2i++)                  \
      ef[q2i] = *(const u16x8*)&(ER)[(q2i * 16 + l15) * 40 + quad * 8];  \
    _Pragma("unroll") for (int ct = 0; ct < 4; ct++)                     \
      _Pragma("unroll") for (int q2i = 0; q2i < 4; q2i++)                \
        acc[q2i][ct] = MFMA16(ef[q2i], bv[ct], acc[q2i][ct]);            \
  }
#define EXPW(EW, SV)                                                     \
  {                                                                      \
    _Pragma("unroll") for (int i = 0; i < 4; i++) {                      \
      float e = __expf(SV[i] + cq4[i]);                                  \
      lp[i] += e;                                                        \
      (EW)[(qg * 16 + quad * 4 + i) * 40 + nh * 16 + l15] = f2bf(e);     \
    }                                                                    \
  }
#define BARRIER()                                                        \
  {                                                                      \
    asm volatile("s_waitcnt lgkmcnt(0)" ::: "memory");                   \
    __builtin_amdgcn_s_barrier();                                        \
    __builtin_amdgcn_sched_barrier(0);                                   \
  }

  // ---- prologue: sub 0 (no PV yet) ----
  LOAD_KF(0);
  LOAD_V(0);
  {
    f32x4 s;
    LOGITS(s);
    EXPW(Es[0], s);
  }

  // ---- main: subs 1..63 ----
#pragma unroll 1
  for (int sub = 1; sub < 64; ++sub) {
    BARRIER();  // publishes Es[(sub-1)&1]; Es[sub&1] free (reads done)
    LOAD_KF(sub);
    __builtin_amdgcn_s_setprio(1);
    PV_STEP(Es[(sub - 1) & 1]);  // uses bv = V(sub-1); covers kf latency
    __builtin_amdgcn_s_setprio(0);
    LOAD_V(sub);
    f32x4 s;
    LOGITS(s);
    EXPW(Es[sub & 1], s);
  }

  // ---- epilogue: PV for sub 63 ----
  BARRIER();
  PV_STEP(Es[1]);

#undef LOAD_KF
#undef LOAD_V
#undef LOGITS
#undef PV_STEP
#undef EXPW
#undef BARRIER

  // combine partials across the 16 N-chunks
#pragma unroll
  for (int q2i = 0; q2i < 4; q2i++)
#pragma unroll
    for (int ct = 0; ct < 4; ct++) {
      int col = colb + ct * 16 + l15;
#pragma unroll
      for (int i = 0; i < 4; i++) {
        int row = qbase + q2i * 16 + quad * 4 + i;
        atomicAdd(&racc[(size_t)row * 512 + col], acc[q2i][ct][i]);
      }
    }
#pragma unroll
  for (int i = 0; i < 4; i++) {
    float v = lp[i];
#pragma unroll
    for (int off = 1; off < 16; off <<= 1) v += __shfl_xor(v, off, 64);
    if (l15 == 0) atomicAdd(&lacc[qbase + qg * 16 + quad * 4 + i], v);
  }
}

// ----------------------- finalize: sigma gate + mix -------------------------
__global__ __launch_bounds__(256) void finalize(
    const float* __restrict__ h, const float* __restrict__ attn,
    const float* __restrict__ prev, const float* __restrict__ wg2,
    const float* __restrict__ bg2, float* __restrict__ out) {
  __shared__ float red[4];
  int r = blockIdx.x, t = threadIdx.x;
  const float* hr = h + (size_t)r * 512;
  float p = hr[t] * wg2[t] + hr[t + 256] * wg2[t + 256];
#pragma unroll
  for (int off = 32; off; off >>= 1) p += __shfl_down(p, off, 64);
  if ((t & 63) == 0) red[t >> 6] = p;
  __syncthreads();
  float dot = red[0] + red[1] + red[2] + red[3];
  float sg = 1.f / (1.f + __expf(-(dot + bg2[0])));
  size_t base = (size_t)r * 512;
  out[base + t] = attn[base + t] * sg + prev[base + t] * (1.f - sg);
  out[base + t + 256] = attn[base + t + 256] * sg + prev[base + t + 256] * (1.f - sg);
}

// ---------------------------------------------------------------------------
extern "C" void kernel_launch(void* const* d_in, const int* in_sizes, int n_in,
                              void* d_out, int out_size, void* d_ws, size_t ws_size,
                              hipStream_t stream) {
  const float* q    = (const float*)d_in[0];
  const float* prev = (const float*)d_in[1];
  const float* Wq   = (const float*)d_in[2];
  const float* bq   = (const float*)d_in[3];
  const float* Wk   = (const float*)d_in[4];
  const float* bk   = (const float*)d_in[5];
  const float* Wv   = (const float*)d_in[6];
  const float* bv   = (const float*)d_in[7];
  const float* Wg1  = (const float*)d_in[8];
  const float* bg1  = (const float*)d_in[9];
  const float* Wg2  = (const float*)d_in[10];
  const float* bg2  = (const float*)d_in[11];
  const float* dk   = (const float*)d_in[12];
  const float* dv   = (const float*)d_in[13];
  float* out = (float*)d_out;

  char* ws = (char*)d_ws;
  u16*   kfr  = (u16*)(ws);                  // 33,554,432 B (fragment-ordered K)
  u16*   vt   = (u16*)(ws + 33554432);       // 33,554,432 B
  float* racc = (float*)(ws + 67108864);     // 2 MB
  float* lacc = (float*)(ws + 69206016);     // 4 KB (contiguous after racc)
  float* cqv  = (float*)(ws + 69210112);     // 4 KB
  u16*   q2   = (u16*)(ws + 69214208);       // 1 MB
  float* q1   = (float*)(ws + 70262784);     // 2 MB (reused as h)
  float* attn = (float*)(ws + 72359936);     // 2 MB   -> total 74,457,088 B
  float* h    = q1;

  prep_kfrag<<<1024, 256, 0, stream>>>(dk, kfr);
  prep_vt<<<dim3(512, 8), 256, 0, stream>>>(dv, vt);
  // q1 = (q @ Wq^T + bq) * D^-0.5
  gemm64<true, false, false, false, false><<<dim3(8, 16), 256, 0, stream>>>(
      q, nullptr, Wq, bq, nullptr, 0.044194173824159216f, q1, 1024, 512, 512);
  cq_kernel<<<1024, 64, 0, stream>>>(q1, bk, cqv);
  // Q2 = (q1 @ Wk) * 2   (bf16)
  gemm64<false, false, false, true, false><<<dim3(8, 16), 256, 0, stream>>>(
      q1, nullptr, Wk, nullptr, nullptr, 2.0f, q2, 1024, 512, 512);
  hipMemsetAsync(racc, 0, 2097152 + 4096, stream);  // racc + lacc
  flash<<<256, 512, 0, stream>>>(kfr, vt, q2, cqv, racc, lacc);
  // attn = (racc/l) @ Wv^T + bv
  gemm64<true, false, false, false, true><<<dim3(8, 16), 256, 0, stream>>>(
      racc, nullptr, Wv, bv, lacc, 1.0f, attn, 1024, 512, 512);
  // h = relu([attn|prev] @ Wg1^T + bg1)
  gemm64<true, true, true, false, false><<<dim3(8, 16), 256, 0, stream>>>(
      attn, prev, Wg1, bg1, nullptr, 1.0f, h, 1024, 512, 1024);
  finalize<<<1024, 256, 0, stream>>>(h, attn, prev, Wg2, bg2, out);
}

// Round 4
// 430.288 us; speedup vs baseline: 1.0024x; 1.0024x over previous
//
#include <hip/hip_runtime.h>
#include <hip/hip_bf16.h>
#include <cstdint>
#include <cstddef>

// ---------------------------------------------------------------------------
// DatastoreReaderLayer: S=256 B=4 D=512 N=32768, TEMP=0.5
// Math restructured:
//   q1 = (q @ Wq^T + bq) * D^-0.5                      [1024,512] fp32
//   Q2 = (q1 @ Wk) * (1/TEMP)  (bf16)   cq = (q1.bk)*(1/TEMP)
//   E[q,n] = exp(Q2[q,:].k_raw[n,:] + cq[q])  (no max-sub; logits ~N(0,1))
//   racc = E @ V_raw (fp32, split-N atomics), l = rowsum(E)
//   attn = (racc/l) @ Wv^T + bv
//   h = relu([attn|prev] @ Wg1^T + bg1); s = sigmoid(h.wg2 + bg2)
//   out = attn*s + prev*(1-s)        (row index qi = s*B+b == input layout!)
// WS BUDGET: needs ws_size >= 74,457,088 bytes (kfr 32MB, vt 32MB, rest ~9MB)
//
// R4 flash: kfr fragment order (R3) + global_load_lds STAGING (R2's traffic
// shape without its costs):
//  - K staged ONCE per block into LDS via global_load_lds width=16 (no VGPR
//    round-trip, no ds_write instrs); fragment-ordered global layout makes
//    the LDS image linear -> satisfies gload_lds uniform-base+lane*16 rule,
//    and ds_read_b128 of fragments is conflict-free.
//  - double-buffered K LDS; ONE raw barrier/sub (m201 template):
//    vmcnt(0)+lgkmcnt(0) (all outstanding loads were issued a FULL region
//    earlier -> wait ~free) + s_barrier + sched_barrier(0). Loads issued at
//    region top (issue-early/consume-late, T14).
//  - PV(s-1) + logits(s) back-to-back in one region under setprio(1).
// ---------------------------------------------------------------------------

typedef unsigned short u16;
typedef u16    u16x8 __attribute__((ext_vector_type(8)));
typedef u16    u16x4 __attribute__((ext_vector_type(4)));
typedef __bf16 bf16x8 __attribute__((ext_vector_type(8)));
typedef float  f32x4 __attribute__((ext_vector_type(4)));

#define MFMA16(a, b, c) __builtin_amdgcn_mfma_f32_16x16x32_bf16( \
    __builtin_bit_cast(bf16x8, (a)), __builtin_bit_cast(bf16x8, (b)), (c), 0, 0, 0)

__device__ __forceinline__ u16 f2bf(float f) {  // RNE float->bf16
  unsigned u = __builtin_bit_cast(unsigned, f);
  u += 0x7fffu + ((u >> 16) & 1u);
  return (u16)(u >> 16);
}

__device__ __forceinline__ void glds16(const u16* g, u16* l) {
  __builtin_amdgcn_global_load_lds(
      (const __attribute__((address_space(1))) unsigned*)g,
      (__attribute__((address_space(3))) unsigned*)l, 16, 0, 0);
}

// ---------- prep: dstore_k fp32 -> bf16 in MFMA-fragment order --------------
// Fragment (gsub, nh, ks): lane ln = quad*16+l15 holds
//   K[gsub*32 + nh*16 + l15][ks*32 + quad*8 + j]  (j=0..7)
// at kfr[gsub*16384 + (nh*16+ks)*512 + ln*8 + j].
__global__ __launch_bounds__(256) void prep_kfrag(const float* __restrict__ src,
                                                  u16* __restrict__ dst) {
  const int sub = blockIdx.x;  // 1024 subs of 32 rows
  const int t = threadIdx.x;
  const float* s0 = src + (size_t)sub * 32 * 512;
  u16* d0 = dst + (size_t)sub * 16384;
#pragma unroll
  for (int u = 0; u < 8; u++) {
    int ci = t + 256 * u;  // cell id 0..2047
    int nh = ci >> 10, ks = (ci >> 6) & 15, ln = ci & 63;
    int qd = ln >> 4, l15 = ln & 15;
    const float* sp = s0 + (size_t)(nh * 16 + l15) * 512 + ks * 32 + qd * 8;
    float4 a = *(const float4*)sp;
    float4 b = *(const float4*)(sp + 4);
    u16x8 o = {f2bf(a.x), f2bf(a.y), f2bf(a.z), f2bf(a.w),
               f2bf(b.x), f2bf(b.y), f2bf(b.z), f2bf(b.w)};
    *(u16x8*)(d0 + (size_t)ci * 8) = o;
  }
}

// --------------- prep: dstore_v -> bf16 transposed [512][32768] -------------
__global__ __launch_bounds__(256) void prep_vt(const float* __restrict__ v,
                                               u16* __restrict__ vt) {
  __shared__ u16 Lt[64 * 72];  // [d_local][n_local+pad]
  const int n0 = blockIdx.x * 64, d0 = blockIdx.y * 64;
  const int t = threadIdx.x;
  const int n = t >> 2, c4 = t & 3;
#pragma unroll
  for (int i = 0; i < 4; i++) {
    int col = (c4 + 4 * i) * 4;
    float4 x = *(const float4*)(v + (size_t)(n0 + n) * 512 + d0 + col);
    Lt[(col + 0) * 72 + n] = f2bf(x.x);
    Lt[(col + 1) * 72 + n] = f2bf(x.y);
    Lt[(col + 2) * 72 + n] = f2bf(x.z);
    Lt[(col + 3) * 72 + n] = f2bf(x.w);
  }
  __syncthreads();
#pragma unroll
  for (int u = 0; u < 2; u++) {
    int unit = t + 256 * u;  // 512 units: 64 d-rows x 8 units of 8 ushorts
    int d = unit >> 3, un = unit & 7;
    *(u16x8*)(vt + (size_t)(d0 + d) * 32768 + n0 + un * 8) =
        *(const u16x8*)&Lt[d * 72 + un * 8];
  }
}

// ---------------- small MFMA GEMM: C = act((A @ op(B) + bias)*alpha) --------
// A [M,K] fp32 row-major (CONCAT: A cols 0..511, A2 cols 512..1023, lda=512)
// TRANSB: B [N,K] (use B rows);  !TRANSB: B [K,N]
// ROWSCALE: A row r scaled by 1/lvec[r] during staging
template <bool TRANSB, bool CONCAT, bool RELU, bool OUTBF16, bool ROWSCALE>
__global__ __launch_bounds__(256, 2) void gemm64(
    const float* __restrict__ A, const float* __restrict__ A2,
    const float* __restrict__ B, const float* __restrict__ bias,
    const float* __restrict__ lvec, float alpha, void* __restrict__ Cv,
    int M, int N, int K) {
  __shared__ u16 As[64 * 72];
  __shared__ u16 Bs[64 * 72];  // [n_local][k_local]
  const int tid = threadIdx.x;
  const int w = tid >> 6, lane = tid & 63, quad = lane >> 4, l15 = lane & 15;
  const int m0 = blockIdx.y * 64, n0 = blockIdx.x * 64;
  const int arow = tid >> 2, ac4 = tid & 3;
  float rs = 1.0f;
  if (ROWSCALE) rs = 1.0f / lvec[m0 + arow];
  const f32x4 fzero = {0.f, 0.f, 0.f, 0.f};
  f32x4 acc[4];
#pragma unroll
  for (int i = 0; i < 4; i++) acc[i] = fzero;

  for (int k0 = 0; k0 < K; k0 += 64) {
    __syncthreads();
    {  // stage A tile (row-major [m][k], bf16)
      const float* src;
      if (CONCAT)
        src = (k0 < 512) ? (A + (size_t)(m0 + arow) * 512 + k0)
                         : (A2 + (size_t)(m0 + arow) * 512 + (k0 - 512));
      else
        src = A + (size_t)(m0 + arow) * K + k0;
#pragma unroll
      for (int i = 0; i < 4; i++) {
        int col = (ac4 + 4 * i) * 4;
        float4 x = *(const float4*)(src + col);
        if (ROWSCALE) { x.x *= rs; x.y *= rs; x.z *= rs; x.w *= rs; }
        u16x4 o = {f2bf(x.x), f2bf(x.y), f2bf(x.z), f2bf(x.w)};
        *(u16x4*)&As[arow * 72 + col] = o;
      }
    }
    if (TRANSB) {  // B [N,K]: rows are n -> same staging pattern
      const float* src = B + (size_t)(n0 + arow) * K + k0;
#pragma unroll
      for (int i = 0; i < 4; i++) {
        int col = (ac4 + 4 * i) * 4;
        float4 x = *(const float4*)(src + col);
        u16x4 o = {f2bf(x.x), f2bf(x.y), f2bf(x.z), f2bf(x.w)};
        *(u16x4*)&Bs[arow * 72 + col] = o;
      }
    } else {  // B [K,N]: transpose into Bs[n][k]
      const float* src = B + (size_t)(k0 + arow) * N + n0;
#pragma unroll
      for (int i = 0; i < 4; i++) {
        int col = (ac4 + 4 * i) * 4;
        float4 x = *(const float4*)(src + col);
        Bs[(col + 0) * 72 + arow] = f2bf(x.x);
        Bs[(col + 1) * 72 + arow] = f2bf(x.y);
        Bs[(col + 2) * 72 + arow] = f2bf(x.z);
        Bs[(col + 3) * 72 + arow] = f2bf(x.w);
      }
    }
    __syncthreads();
#pragma unroll
    for (int ks = 0; ks < 2; ks++) {
      u16x8 af = *(const u16x8*)&As[(w * 16 + l15) * 72 + ks * 32 + quad * 8];
#pragma unroll
      for (int nt = 0; nt < 4; nt++) {
        u16x8 bf = *(const u16x8*)&Bs[(nt * 16 + l15) * 72 + ks * 32 + quad * 8];
        acc[nt] = MFMA16(af, bf, acc[nt]);
      }
    }
  }
#pragma unroll
  for (int nt = 0; nt < 4; nt++) {
    int col = n0 + nt * 16 + l15;
    float b = bias ? bias[col] : 0.f;
#pragma unroll
    for (int i = 0; i < 4; i++) {
      int row = m0 + w * 16 + quad * 4 + i;
      float y = (acc[nt][i] + b) * alpha;
      if (RELU) y = fmaxf(y, 0.f);
      if (OUTBF16)
        ((u16*)Cv)[(size_t)row * N + col] = f2bf(y);
      else
        ((float*)Cv)[(size_t)row * N + col] = y;
    }
  }
}

// ----------------------------- cq = 2*(q1 . bk) -----------------------------
__global__ void cq_kernel(const float* __restrict__ q1,
                          const float* __restrict__ bk,
                          float* __restrict__ cq) {
  int r = blockIdx.x, lane = threadIdx.x;  // 64 threads = 1 wave
  float s = 0.f;
#pragma unroll
  for (int k = 0; k < 512; k += 64) s += q1[(size_t)r * 512 + k + lane] * bk[k + lane];
#pragma unroll
  for (int off = 32; off; off >>= 1) s += __shfl_down(s, off, 64);
  if (lane == 0) cq[r] = 2.0f * s;
}

// ------------------------------- flash kernel -------------------------------
// grid 256, 8 waves. XCD remap: x=bx&7 (XCD), j=bx>>3; ch=2x+(j&1), qt=j>>1.
// wave w: logits rows qg=w>>1 (16q) x n-half nh=w&1 (16n of 32);
//         PV: all 64q x cols [w*64, w*64+64).
// Per sub (ONE raw barrier, m201-template):
//   [vmcnt(0) lgkmcnt(0); s_barrier; sched_barrier]   <- waits loads issued
//   GLDS K(s+1)->buf[(s+1)&1]; LOAD_V(s)                 one region ago
//   PV(Es[(s-1)&1], V(s-1)) ; LOGITS(buf[s&1]) ; EXPW -> Es[s&1]
__global__ __launch_bounds__(512, 2) void flash(
    const u16* __restrict__ kfr,  // fragment-ordered K (see prep_kfrag)
    const u16* __restrict__ vt,   // [512][32768] bf16 (transposed V)
    const u16* __restrict__ q2,   // [1024][512] bf16 (scaled 2*(q1@Wk))
    const float* __restrict__ cq, // [1024]
    float* __restrict__ racc,     // [1024][512] fp32, pre-zeroed
    float* __restrict__ lacc) {   // [1024] fp32, pre-zeroed
  __shared__ __align__(16) u16 Kb[2][16384];  // 2 x 32KB K sub-tiles (linear)
  __shared__ __align__(16) u16 Es[2][64 * 40];
  const int tid = threadIdx.x;
  const int w = tid >> 6, lane = tid & 63, quad = lane >> 4, l15 = lane & 15;
  const int x = blockIdx.x & 7, j = blockIdx.x >> 3;
  const int ch = 2 * x + (j & 1), qt = j >> 1;
  const int qbase = qt * 64;
  const int qg = w >> 1, nh = w & 1;
  const int colb = w * 64;

  // Q fragments: 16 x (16q x 32d) in registers (64 VGPRs)
  u16x8 qf[16];
  {
    const u16* qp = q2 + (size_t)(qbase + qg * 16 + l15) * 512 + quad * 8;
#pragma unroll
    for (int ks = 0; ks < 16; ks++) qf[ks] = *(const u16x8*)(qp + ks * 32);
  }
  float cq4[4];
#pragma unroll
  for (int i = 0; i < 4; i++) cq4[i] = cq[qbase + qg * 16 + quad * 4 + i];
  float lp[4] = {0.f, 0.f, 0.f, 0.f};
  const f32x4 fzero = {0.f, 0.f, 0.f, 0.f};
  f32x4 acc[4][4];
#pragma unroll
  for (int a = 0; a < 4; a++)
#pragma unroll
    for (int b = 0; b < 4; b++) acc[a][b] = fzero;

  // global K base for this wave's staging share (4KB per wave per sub)
  const u16* kg0 = kfr + (size_t)(ch * 64) * 16384 + w * 2048 + lane * 8;
  // V base: vt[(colb+ct*16+l15)*32768 + ch*2048 + sub*32 + quad*8]
  const u16* vp0 = vt + (size_t)(colb + l15) * 32768 + ch * 2048 + quad * 8;

  u16x8 bvA[4], bvB[4];  // V fragments ping-pong (consumed 1 sub later)

#define GLDS_K(SUB, BI)                                                  \
  {                                                                      \
    const u16* gb = kg0 + (size_t)(SUB) * 16384;                         \
    _Pragma("unroll") for (int u = 0; u < 4; u++)                        \
        glds16(gb + u * 512, &Kb[BI][w * 2048 + u * 512]);               \
  }
#define LOAD_V(BV, SUB)                                                  \
  {                                                                      \
    _Pragma("unroll") for (int ct = 0; ct < 4; ct++)                     \
        BV[ct] = *(const u16x8*)(vp0 + (size_t)ct * (16 * 32768) +       \
                                 (SUB) * 32);                            \
  }
#define LOGITS(BI, SV)                                                   \
  {                                                                      \
    f32x4 s0_ = fzero, s1_ = fzero;                                      \
    const u16* kb_ = &Kb[BI][nh * 8192 + lane * 8];                      \
    _Pragma("unroll") for (int ks = 0; ks < 16; ks += 2) {               \
      u16x8 k0_ = *(const u16x8*)(kb_ + ks * 512);                       \
      u16x8 k1_ = *(const u16x8*)(kb_ + (ks + 1) * 512);                 \
      s0_ = MFMA16(qf[ks], k0_, s0_);                                    \
      s1_ = MFMA16(qf[ks + 1], k1_, s1_);                                \
    }                                                                    \
    SV = s0_ + s1_;                                                      \
  }
#define PV_STEP(ER, BV)                                                  \
  {                                                                      \
    u16x8 ef[4];                                                         \
    _Pragma("unroll") for (int q2i = 0; q2i < 4; q2i++)                  \
      ef[q2i] = *(const u16x8*)&(ER)[(q2i * 16 + l15) * 40 + quad * 8];  \
    _Pragma("unroll") for (int ct = 0; ct < 4; ct++)                     \
      _Pragma("unroll") for (int q2i = 0; q2i < 4; q2i++)                \
        acc[q2i][ct] = MFMA16(ef[q2i], BV[ct], acc[q2i][ct]);            \
  }
#define EXPW(EW, SV)                                                     \
  {                                                                      \
    _Pragma("unroll") for (int i = 0; i < 4; i++) {                      \
      float e = __expf(SV[i] + cq4[i]);                                  \
      lp[i] += e;                                                        \
      (EW)[(qg * 16 + quad * 4 + i) * 40 + nh * 16 + l15] = f2bf(e);     \
    }                                                                    \
  }
#define WAIT_BAR(VN)                                                     \
  {                                                                      \
    asm volatile("s_waitcnt vmcnt(" #VN ") lgkmcnt(0)" ::: "memory");    \
    __builtin_amdgcn_s_barrier();                                        \
    __builtin_amdgcn_sched_barrier(0);                                   \
  }

  // ---- prologue: stage K(0),K(1); V(0); logits(0) ----
  GLDS_K(0, 0);                       // vm 4
  GLDS_K(1, 1);                       // vm 8
  LOAD_V(bvA, 0);                     // vm 12
  asm volatile("s_waitcnt vmcnt(8)" ::: "memory");  // own K(0) share landed
  __builtin_amdgcn_s_barrier();       // all waves' K(0) landed
  __builtin_amdgcn_sched_barrier(0);
  {
    f32x4 s;
    LOGITS(0, s);
    EXPW(Es[0], s);
  }

  // ---- main: subs 1..62 in odd/even pairs (static reg/buffer parity) ----
#pragma unroll 1
  for (int sb = 1; sb < 62; sb += 2) {
    // odd s = sb: read buf1/Es[0]/bvA; stage K(s+1)->buf0, V(s)->bvB
    WAIT_BAR(0);  // K(s),V(s-1) done (issued 1 region ago); Es published
    GLDS_K(sb + 1, 0);
    LOAD_V(bvB, sb);
    __builtin_amdgcn_sched_barrier(0);  // pin load issue before MFMA region
    __builtin_amdgcn_s_setprio(1);
    f32x4 s;
    PV_STEP(Es[0], bvA);
    LOGITS(1, s);
    __builtin_amdgcn_s_setprio(0);
    EXPW(Es[1], s);
    // even s = sb+1: read buf0/Es[1]/bvB; stage K(s+1)->buf1, V(s)->bvA
    WAIT_BAR(0);
    GLDS_K(sb + 2, 1);
    LOAD_V(bvA, sb + 1);
    __builtin_amdgcn_sched_barrier(0);
    __builtin_amdgcn_s_setprio(1);
    f32x4 t;
    PV_STEP(Es[1], bvB);
    LOGITS(0, t);
    __builtin_amdgcn_s_setprio(0);
    EXPW(Es[0], t);
  }

  // ---- sub 63 (odd; no K prefetch) ----
  WAIT_BAR(0);
  LOAD_V(bvB, 63);
  __builtin_amdgcn_sched_barrier(0);
  {
    __builtin_amdgcn_s_setprio(1);
    f32x4 s;
    PV_STEP(Es[0], bvA);
    LOGITS(1, s);
    __builtin_amdgcn_s_setprio(0);
    EXPW(Es[1], s);
  }
  // ---- epilogue: PV for sub 63 ----
  WAIT_BAR(0);
  PV_STEP(Es[1], bvB);

#undef GLDS_K
#undef LOAD_V
#undef LOGITS
#undef PV_STEP
#undef EXPW
#undef WAIT_BAR

  // combine partials across the 16 N-chunks
#pragma unroll
  for (int q2i = 0; q2i < 4; q2i++)
#pragma unroll
    for (int ct = 0; ct < 4; ct++) {
      int col = colb + ct * 16 + l15;
#pragma unroll
      for (int i = 0; i < 4; i++) {
        int row = qbase + q2i * 16 + quad * 4 + i;
        atomicAdd(&racc[(size_t)row * 512 + col], acc[q2i][ct][i]);
      }
    }
#pragma unroll
  for (int i = 0; i < 4; i++) {
    float v = lp[i];
#pragma unroll
    for (int off = 1; off < 16; off <<= 1) v += __shfl_xor(v, off, 64);
    if (l15 == 0) atomicAdd(&lacc[qbase + qg * 16 + quad * 4 + i], v);
  }
}

// ----------------------- finalize: sigma gate + mix -------------------------
__global__ __launch_bounds__(256) void finalize(
    const float* __restrict__ h, const float* __restrict__ attn,
    const float* __restrict__ prev, const float* __restrict__ wg2,
    const float* __restrict__ bg2, float* __restrict__ out) {
  __shared__ float red[4];
  int r = blockIdx.x, t = threadIdx.x;
  const float* hr = h + (size_t)r * 512;
  float p = hr[t] * wg2[t] + hr[t + 256] * wg2[t + 256];
#pragma unroll
  for (int off = 32; off; off >>= 1) p += __shfl_down(p, off, 64);
  if ((t & 63) == 0) red[t >> 6] = p;
  __syncthreads();
  float dot = red[0] + red[1] + red[2] + red[3];
  float sg = 1.f / (1.f + __expf(-(dot + bg2[0])));
  size_t base = (size_t)r * 512;
  out[base + t] = attn[base + t] * sg + prev[base + t] * (1.f - sg);
  out[base + t + 256] = attn[base + t + 256] * sg + prev[base + t + 256] * (1.f - sg);
}

// ---------------------------------------------------------------------------
extern "C" void kernel_launch(void* const* d_in, const int* in_sizes, int n_in,
                              void* d_out, int out_size, void* d_ws, size_t ws_size,
                              hipStream_t stream) {
  const float* q    = (const float*)d_in[0];
  const float* prev = (const float*)d_in[1];
  const float* Wq   = (const float*)d_in[2];
  const float* bq   = (const float*)d_in[3];
  const float* Wk   = (const float*)d_in[4];
  const float* bk   = (const float*)d_in[5];
  const float* Wv   = (const float*)d_in[6];
  const float* bv   = (const float*)d_in[7];
  const float* Wg1  = (const float*)d_in[8];
  const float* bg1  = (const float*)d_in[9];
  const float* Wg2  = (const float*)d_in[10];
  const float* bg2  = (const float*)d_in[11];
  const float* dk   = (const float*)d_in[12];
  const float* dv   = (const float*)d_in[13];
  float* out = (float*)d_out;

  char* ws = (char*)d_ws;
  u16*   kfr  = (u16*)(ws);                  // 33,554,432 B (fragment-ordered K)
  u16*   vt   = (u16*)(ws + 33554432);       // 33,554,432 B
  float* racc = (float*)(ws + 67108864);     // 2 MB
  float* lacc = (float*)(ws + 69206016);     // 4 KB (contiguous after racc)
  float* cqv  = (float*)(ws + 69210112);     // 4 KB
  u16*   q2   = (u16*)(ws + 69214208);       // 1 MB
  float* q1   = (float*)(ws + 70262784);     // 2 MB (reused as h)
  float* attn = (float*)(ws + 72359936);     // 2 MB   -> total 74,457,088 B
  float* h    = q1;

  prep_kfrag<<<1024, 256, 0, stream>>>(dk, kfr);
  prep_vt<<<dim3(512, 8), 256, 0, stream>>>(dv, vt);
  // q1 = (q @ Wq^T + bq) * D^-0.5
  gemm64<true, false, false, false, false><<<dim3(8, 16), 256, 0, stream>>>(
      q, nullptr, Wq, bq, nullptr, 0.044194173824159216f, q1, 1024, 512, 512);
  cq_kernel<<<1024, 64, 0, stream>>>(q1, bk, cqv);
  // Q2 = (q1 @ Wk) * 2   (bf16)
  gemm64<false, false, false, true, false><<<dim3(8, 16), 256, 0, stream>>>(
      q1, nullptr, Wk, nullptr, nullptr, 2.0f, q2, 1024, 512, 512);
  hipMemsetAsync(racc, 0, 2097152 + 4096, stream);  // racc + lacc
  flash<<<256, 512, 0, stream>>>(kfr, vt, q2, cqv, racc, lacc);
  // attn = (racc/l) @ Wv^T + bv
  gemm64<true, false, false, false, true><<<dim3(8, 16), 256, 0, stream>>>(
      racc, nullptr, Wv, bv, lacc, 1.0f, attn, 1024, 512, 512);
  // h = relu([attn|prev] @ Wg1^T + bg1)
  gemm64<true, true, true, false, false><<<dim3(8, 16), 256, 0, stream>>>(
      attn, prev, Wg1, bg1, nullptr, 1.0f, h, 1024, 512, 1024);
  finalize<<<1024, 256, 0, stream>>>(h, attn, prev, Wg2, bg2, out);
}

// Round 5
// 419.400 us; speedup vs baseline: 1.0284x; 1.0260x over previous
//
#include <hip/hip_runtime.h>
#include <hip/hip_bf16.h>
#include <cstdint>
#include <cstddef>

// ---------------------------------------------------------------------------
// DatastoreReaderLayer: S=256 B=4 D=512 N=32768, TEMP=0.5
// Math restructured:
//   q1 = (q @ Wq^T + bq) * D^-0.5                      [1024,512] fp32
//   Q2 = (q1 @ Wk) * (1/TEMP)  (bf16)   cq = (q1.bk)*(1/TEMP)
//   E[q,n] = exp(Q2[q,:].k_raw[n,:] + cq[q])  (no max-sub; logits ~N(0,1))
//   racc = E @ V_raw (fp32, split-N atomics), l = rowsum(E)
//   attn = (racc/l) @ Wv^T + bv
//   h = relu([attn|prev] @ Wg1^T + bg1); s = sigmoid(h.wg2 + bg2)
//   out = attn*s + prev*(1-s)        (row index qi = s*B+b == input layout!)
// WS BUDGET: needs ws_size >= 74,457,088 bytes (kfr 32MB, vt 32MB, rest ~9MB)
//
// R5 flash: COUNTED vmcnt pipeline (T4). R2/R3/R4 all drained vmcnt to 0 (or
// let in-order retirement do it implicitly) -> depth-1 pipeline, ~5900cyc/sub
// of latency serialization. Now:
//  - Kb 4-deep (128KB LDS): K(s+3) issued region s via global_load_lds w=16,
//    consumed region s+3 (ds_read of fragment-linear image, conflict-free).
//  - V issued BEFORE K in each region: vmcnt retires IN ORDER, so PV(s-1)'s
//    implicit wait for V(s-1) leaves the K prefetches in flight.
//  - barrier wait = vmcnt(12)+lgkmcnt(0), NEVER 0: retires exactly K(s)
//    (this region's ds_read source), keeps 12 newer loads airborne.
//  - 4-unrolled main loop with literal phase P so every buffer index is a
//    compile-time constant (no scratch spills).
// ---------------------------------------------------------------------------

typedef unsigned short u16;
typedef u16    u16x8 __attribute__((ext_vector_type(8)));
typedef u16    u16x4 __attribute__((ext_vector_type(4)));
typedef __bf16 bf16x8 __attribute__((ext_vector_type(8)));
typedef float  f32x4 __attribute__((ext_vector_type(4)));

#define MFMA16(a, b, c) __builtin_amdgcn_mfma_f32_16x16x32_bf16( \
    __builtin_bit_cast(bf16x8, (a)), __builtin_bit_cast(bf16x8, (b)), (c), 0, 0, 0)

__device__ __forceinline__ u16 f2bf(float f) {  // RNE float->bf16
  unsigned u = __builtin_bit_cast(unsigned, f);
  u += 0x7fffu + ((u >> 16) & 1u);
  return (u16)(u >> 16);
}

__device__ __forceinline__ void glds16(const u16* g, u16* l) {
  __builtin_amdgcn_global_load_lds(
      (const __attribute__((address_space(1))) unsigned*)g,
      (__attribute__((address_space(3))) unsigned*)l, 16, 0, 0);
}

// ---------- prep: dstore_k fp32 -> bf16 in MFMA-fragment order --------------
// Fragment (gsub, nh, ks): lane ln = quad*16+l15 holds
//   K[gsub*32 + nh*16 + l15][ks*32 + quad*8 + j]  (j=0..7)
// at kfr[gsub*16384 + (nh*16+ks)*512 + ln*8 + j].
__global__ __launch_bounds__(256) void prep_kfrag(const float* __restrict__ src,
                                                  u16* __restrict__ dst) {
  const int sub = blockIdx.x;  // 1024 subs of 32 rows
  const int t = threadIdx.x;
  const float* s0 = src + (size_t)sub * 32 * 512;
  u16* d0 = dst + (size_t)sub * 16384;
#pragma unroll
  for (int u = 0; u < 8; u++) {
    int ci = t + 256 * u;  // cell id 0..2047
    int nh = ci >> 10, ks = (ci >> 6) & 15, ln = ci & 63;
    int qd = ln >> 4, l15 = ln & 15;
    const float* sp = s0 + (size_t)(nh * 16 + l15) * 512 + ks * 32 + qd * 8;
    float4 a = *(const float4*)sp;
    float4 b = *(const float4*)(sp + 4);
    u16x8 o = {f2bf(a.x), f2bf(a.y), f2bf(a.z), f2bf(a.w),
               f2bf(b.x), f2bf(b.y), f2bf(b.z), f2bf(b.w)};
    *(u16x8*)(d0 + (size_t)ci * 8) = o;
  }
}

// --------------- prep: dstore_v -> bf16 transposed [512][32768] -------------
__global__ __launch_bounds__(256) void prep_vt(const float* __restrict__ v,
                                               u16* __restrict__ vt) {
  __shared__ u16 Lt[64 * 72];  // [d_local][n_local+pad]
  const int n0 = blockIdx.x * 64, d0 = blockIdx.y * 64;
  const int t = threadIdx.x;
  const int n = t >> 2, c4 = t & 3;
#pragma unroll
  for (int i = 0; i < 4; i++) {
    int col = (c4 + 4 * i) * 4;
    float4 x = *(const float4*)(v + (size_t)(n0 + n) * 512 + d0 + col);
    Lt[(col + 0) * 72 + n] = f2bf(x.x);
    Lt[(col + 1) * 72 + n] = f2bf(x.y);
    Lt[(col + 2) * 72 + n] = f2bf(x.z);
    Lt[(col + 3) * 72 + n] = f2bf(x.w);
  }
  __syncthreads();
#pragma unroll
  for (int u = 0; u < 2; u++) {
    int unit = t + 256 * u;  // 512 units: 64 d-rows x 8 units of 8 ushorts
    int d = unit >> 3, un = unit & 7;
    *(u16x8*)(vt + (size_t)(d0 + d) * 32768 + n0 + un * 8) =
        *(const u16x8*)&Lt[d * 72 + un * 8];
  }
}

// ---------------- small MFMA GEMM: C = act((A @ op(B) + bias)*alpha) --------
// A [M,K] fp32 row-major (CONCAT: A cols 0..511, A2 cols 512..1023, lda=512)
// TRANSB: B [N,K] (use B rows);  !TRANSB: B [K,N]
// ROWSCALE: A row r scaled by 1/lvec[r] during staging
template <bool TRANSB, bool CONCAT, bool RELU, bool OUTBF16, bool ROWSCALE>
__global__ __launch_bounds__(256, 2) void gemm64(
    const float* __restrict__ A, const float* __restrict__ A2,
    const float* __restrict__ B, const float* __restrict__ bias,
    const float* __restrict__ lvec, float alpha, void* __restrict__ Cv,
    int M, int N, int K) {
  __shared__ u16 As[64 * 72];
  __shared__ u16 Bs[64 * 72];  // [n_local][k_local]
  const int tid = threadIdx.x;
  const int w = tid >> 6, lane = tid & 63, quad = lane >> 4, l15 = lane & 15;
  const int m0 = blockIdx.y * 64, n0 = blockIdx.x * 64;
  const int arow = tid >> 2, ac4 = tid & 3;
  float rs = 1.0f;
  if (ROWSCALE) rs = 1.0f / lvec[m0 + arow];
  const f32x4 fzero = {0.f, 0.f, 0.f, 0.f};
  f32x4 acc[4];
#pragma unroll
  for (int i = 0; i < 4; i++) acc[i] = fzero;

  for (int k0 = 0; k0 < K; k0 += 64) {
    __syncthreads();
    {  // stage A tile (row-major [m][k], bf16)
      const float* src;
      if (CONCAT)
        src = (k0 < 512) ? (A + (size_t)(m0 + arow) * 512 + k0)
                         : (A2 + (size_t)(m0 + arow) * 512 + (k0 - 512));
      else
        src = A + (size_t)(m0 + arow) * K + k0;
#pragma unroll
      for (int i = 0; i < 4; i++) {
        int col = (ac4 + 4 * i) * 4;
        float4 x = *(const float4*)(src + col);
        if (ROWSCALE) { x.x *= rs; x.y *= rs; x.z *= rs; x.w *= rs; }
        u16x4 o = {f2bf(x.x), f2bf(x.y), f2bf(x.z), f2bf(x.w)};
        *(u16x4*)&As[arow * 72 + col] = o;
      }
    }
    if (TRANSB) {  // B [N,K]: rows are n -> same staging pattern
      const float* src = B + (size_t)(n0 + arow) * K + k0;
#pragma unroll
      for (int i = 0; i < 4; i++) {
        int col = (ac4 + 4 * i) * 4;
        float4 x = *(const float4*)(src + col);
        u16x4 o = {f2bf(x.x), f2bf(x.y), f2bf(x.z), f2bf(x.w)};
        *(u16x4*)&Bs[arow * 72 + col] = o;
      }
    } else {  // B [K,N]: transpose into Bs[n][k]
      const float* src = B + (size_t)(k0 + arow) * N + n0;
#pragma unroll
      for (int i = 0; i < 4; i++) {
        int col = (ac4 + 4 * i) * 4;
        float4 x = *(const float4*)(src + col);
        Bs[(col + 0) * 72 + arow] = f2bf(x.x);
        Bs[(col + 1) * 72 + arow] = f2bf(x.y);
        Bs[(col + 2) * 72 + arow] = f2bf(x.z);
        Bs[(col + 3) * 72 + arow] = f2bf(x.w);
      }
    }
    __syncthreads();
#pragma unroll
    for (int ks = 0; ks < 2; ks++) {
      u16x8 af = *(const u16x8*)&As[(w * 16 + l15) * 72 + ks * 32 + quad * 8];
#pragma unroll
      for (int nt = 0; nt < 4; nt++) {
        u16x8 bf = *(const u16x8*)&Bs[(nt * 16 + l15) * 72 + ks * 32 + quad * 8];
        acc[nt] = MFMA16(af, bf, acc[nt]);
      }
    }
  }
#pragma unroll
  for (int nt = 0; nt < 4; nt++) {
    int col = n0 + nt * 16 + l15;
    float b = bias ? bias[col] : 0.f;
#pragma unroll
    for (int i = 0; i < 4; i++) {
      int row = m0 + w * 16 + quad * 4 + i;
      float y = (acc[nt][i] + b) * alpha;
      if (RELU) y = fmaxf(y, 0.f);
      if (OUTBF16)
        ((u16*)Cv)[(size_t)row * N + col] = f2bf(y);
      else
        ((float*)Cv)[(size_t)row * N + col] = y;
    }
  }
}

// ----------------------------- cq = 2*(q1 . bk) -----------------------------
__global__ void cq_kernel(const float* __restrict__ q1,
                          const float* __restrict__ bk,
                          float* __restrict__ cq) {
  int r = blockIdx.x, lane = threadIdx.x;  // 64 threads = 1 wave
  float s = 0.f;
#pragma unroll
  for (int k = 0; k < 512; k += 64) s += q1[(size_t)r * 512 + k + lane] * bk[k + lane];
#pragma unroll
  for (int off = 32; off; off >>= 1) s += __shfl_down(s, off, 64);
  if (lane == 0) cq[r] = 2.0f * s;
}

// ------------------------------- flash kernel -------------------------------
// grid 256, 8 waves. XCD remap: x=bx&7 (XCD), j=bx>>3; ch=2x+(j&1), qt=j>>1.
// wave w: logits rows qg=w>>1 (16q) x n-half nh=w&1 (16n of 32);
//         PV: all 64q x cols [w*64, w*64+64).
// Region s (one barrier, COUNTED waits):
//   [vmcnt(12) lgkm(0); s_barrier; sched_barrier]   <- retires K(s) only
//   LOAD_V(s) -> bvv[s&1]     (V first: in-order retire must not drain K!)
//   GLDS_K(s+3) -> Kb[(s+3)&3]
//   PV(s-1) [implicit wait for V(s-1) leaves K(s+2),K(s+3),V(s) in flight]
//   LOGITS(s) from Kb[s&3] ; exp -> Es[s&1]
__global__ __launch_bounds__(512, 2) void flash(
    const u16* __restrict__ kfr,  // fragment-ordered K (see prep_kfrag)
    const u16* __restrict__ vt,   // [512][32768] bf16 (transposed V)
    const u16* __restrict__ q2,   // [1024][512] bf16 (scaled 2*(q1@Wk))
    const float* __restrict__ cq, // [1024]
    float* __restrict__ racc,     // [1024][512] fp32, pre-zeroed
    float* __restrict__ lacc) {   // [1024] fp32, pre-zeroed
  __shared__ __align__(16) u16 Kb[4][16384];  // 4-deep K pipeline (128KB)
  __shared__ __align__(16) u16 Es[2][64 * 40];
  const int tid = threadIdx.x;
  const int w = tid >> 6, lane = tid & 63, quad = lane >> 4, l15 = lane & 15;
  const int x = blockIdx.x & 7, j = blockIdx.x >> 3;
  const int ch = 2 * x + (j & 1), qt = j >> 1;
  const int qbase = qt * 64;
  const int qg = w >> 1, nh = w & 1;
  const int colb = w * 64;

  // Q fragments: 16 x (16q x 32d) in registers (64 VGPRs)
  u16x8 qf[16];
  {
    const u16* qp = q2 + (size_t)(qbase + qg * 16 + l15) * 512 + quad * 8;
#pragma unroll
    for (int ks = 0; ks < 16; ks++) qf[ks] = *(const u16x8*)(qp + ks * 32);
  }
  float cq4[4];
#pragma unroll
  for (int i = 0; i < 4; i++) cq4[i] = cq[qbase + qg * 16 + quad * 4 + i];
  float lp[4] = {0.f, 0.f, 0.f, 0.f};
  const f32x4 fzero = {0.f, 0.f, 0.f, 0.f};
  f32x4 acc[4][4];
#pragma unroll
  for (int a = 0; a < 4; a++)
#pragma unroll
    for (int b = 0; b < 4; b++) acc[a][b] = fzero;

  // global K base for this wave's staging share (4KB per wave per sub)
  const u16* kg0 = kfr + (size_t)(ch * 64) * 16384 + w * 2048 + lane * 8;
  // V base: vt[(colb+ct*16+l15)*32768 + ch*2048 + sub*32 + quad*8]
  const u16* vp0 = vt + (size_t)(colb + l15) * 32768 + ch * 2048 + quad * 8;

  u16x8 bvv[2][4];  // V fragments, ping-pong; ALL indices compile-time

#define GLDS_K(SUB, BI)                                                  \
  {                                                                      \
    const u16* gb = kg0 + (size_t)(SUB) * 16384;                         \
    _Pragma("unroll") for (int u = 0; u < 4; u++)                        \
        glds16(gb + u * 512, &Kb[BI][w * 2048 + u * 512]);               \
  }
#define LOAD_V(BP, SUB)                                                  \
  {                                                                      \
    _Pragma("unroll") for (int ct = 0; ct < 4; ct++)                     \
        bvv[BP][ct] = *(const u16x8*)(vp0 + (size_t)ct * (16 * 32768) +  \
                                      (SUB) * 32);                       \
  }
#define LOGITS(BI, SV)                                                   \
  {                                                                      \
    f32x4 s0_ = fzero, s1_ = fzero;                                      \
    const u16* kb_ = &Kb[BI][nh * 8192 + lane * 8];                      \
    _Pragma("unroll") for (int ks = 0; ks < 16; ks += 2) {               \
      u16x8 k0_ = *(const u16x8*)(kb_ + ks * 512);                       \
      u16x8 k1_ = *(const u16x8*)(kb_ + (ks + 1) * 512);                 \
      s0_ = MFMA16(qf[ks], k0_, s0_);                                    \
      s1_ = MFMA16(qf[ks + 1], k1_, s1_);                                \
    }                                                                    \
    SV = s0_ + s1_;                                                      \
  }
#define PV_STEP(ER, BP)                                                  \
  {                                                                      \
    u16x8 ef[4];                                                         \
    _Pragma("unroll") for (int q2i = 0; q2i < 4; q2i++)                  \
      ef[q2i] = *(const u16x8*)&(ER)[(q2i * 16 + l15) * 40 + quad * 8];  \
    _Pragma("unroll") for (int ct = 0; ct < 4; ct++)                     \
      _Pragma("unroll") for (int q2i = 0; q2i < 4; q2i++)                \
        acc[q2i][ct] = MFMA16(ef[q2i], bvv[BP][ct], acc[q2i][ct]);       \
  }
#define EXPW(EW, SV)                                                     \
  {                                                                      \
    _Pragma("unroll") for (int i = 0; i < 4; i++) {                      \
      float e = __expf(SV[i] + cq4[i]);                                  \
      lp[i] += e;                                                        \
      (EW)[(qg * 16 + quad * 4 + i) * 40 + nh * 16 + l15] = f2bf(e);     \
    }                                                                    \
  }
#define WB(N)                                                            \
  {                                                                      \
    asm volatile("s_waitcnt vmcnt(" #N ") lgkmcnt(0)" ::: "memory");     \
    __builtin_amdgcn_s_barrier();                                        \
    __builtin_amdgcn_sched_barrier(0);                                   \
  }
// uniform region body; S runtime-ok, P MUST be a literal 0..3
#define REGION(S, P)                                                     \
  {                                                                      \
    WB(12);                                                              \
    LOAD_V((P) & 1, (S));                                                \
    GLDS_K((S) + 3, ((P) + 3) & 3);                                      \
    __builtin_amdgcn_sched_barrier(0);                                   \
    __builtin_amdgcn_s_setprio(1);                                       \
    f32x4 sv_;                                                           \
    PV_STEP(Es[((P) + 1) & 1], ((P) + 1) & 1);                           \
    LOGITS((P) & 3, sv_);                                                \
    __builtin_amdgcn_s_setprio(0);                                       \
    EXPW(Es[(P) & 1], sv_);                                              \
  }
#define REGION_NOK(S, P)                                                 \
  {                                                                      \
    WB(12);                                                              \
    LOAD_V((P) & 1, (S));                                                \
    __builtin_amdgcn_sched_barrier(0);                                   \
    __builtin_amdgcn_s_setprio(1);                                       \
    f32x4 sv_;                                                           \
    PV_STEP(Es[((P) + 1) & 1], ((P) + 1) & 1);                           \
    LOGITS((P) & 3, sv_);                                                \
    __builtin_amdgcn_s_setprio(0);                                       \
    EXPW(Es[(P) & 1], sv_);                                              \
  }

  // ---- prologue: K(0..2) in flight; retire only K(0) ----
  GLDS_K(0, 0);
  GLDS_K(1, 1);
  GLDS_K(2, 2);
  asm volatile("s_waitcnt vmcnt(8)" ::: "memory");  // K0 done; K1,K2 in flight
  __builtin_amdgcn_s_barrier();
  __builtin_amdgcn_sched_barrier(0);

  // ---- region 0 (P=0, no PV) ----
  {
    LOAD_V(0, 0);
    GLDS_K(3, 3);
    __builtin_amdgcn_sched_barrier(0);
    __builtin_amdgcn_s_setprio(1);
    f32x4 sv_;
    LOGITS(0, sv_);
    __builtin_amdgcn_s_setprio(0);
    EXPW(Es[0], sv_);
  }
  // ---- region 1 (P=1) ----
  REGION(1, 1);

  // ---- main: regions 2..57, phases (2,3,0,1) ----
#pragma unroll 1
  for (int s0 = 2; s0 < 58; s0 += 4) {
    REGION(s0 + 0, 2);
    REGION(s0 + 1, 3);
    REGION(s0 + 2, 0);
    REGION(s0 + 3, 1);
  }
  // ---- tail with K-issue: K61..K63 ----
  REGION(58, 2);
  REGION(59, 3);
  REGION(60, 0);
  // ---- tail without K-issue ----
  REGION_NOK(61, 1);
  REGION_NOK(62, 2);
  REGION_NOK(63, 3);
  // ---- epilogue: PV(63) ----
  WB(0);
  PV_STEP(Es[1], 1);

#undef GLDS_K
#undef LOAD_V
#undef LOGITS
#undef PV_STEP
#undef EXPW
#undef WB
#undef REGION
#undef REGION_NOK

  // combine partials across the 16 N-chunks
#pragma unroll
  for (int q2i = 0; q2i < 4; q2i++)
#pragma unroll
    for (int ct = 0; ct < 4; ct++) {
      int col = colb + ct * 16 + l15;
#pragma unroll
      for (int i = 0; i < 4; i++) {
        int row = qbase + q2i * 16 + quad * 4 + i;
        atomicAdd(&racc[(size_t)row * 512 + col], acc[q2i][ct][i]);
      }
    }
#pragma unroll
  for (int i = 0; i < 4; i++) {
    float v = lp[i];
#pragma unroll
    for (int off = 1; off < 16; off <<= 1) v += __shfl_xor(v, off, 64);
    if (l15 == 0) atomicAdd(&lacc[qbase + qg * 16 + quad * 4 + i], v);
  }
}

// ----------------------- finalize: sigma gate + mix -------------------------
__global__ __launch_bounds__(256) void finalize(
    const float* __restrict__ h, const float* __restrict__ attn,
    const float* __restrict__ prev, const float* __restrict__ wg2,
    const float* __restrict__ bg2, float* __restrict__ out) {
  __shared__ float red[4];
  int r = blockIdx.x, t = threadIdx.x;
  const float* hr = h + (size_t)r * 512;
  float p = hr[t] * wg2[t] + hr[t + 256] * wg2[t + 256];
#pragma unroll
  for (int off = 32; off; off >>= 1) p += __shfl_down(p, off, 64);
  if ((t & 63) == 0) red[t >> 6] = p;
  __syncthreads();
  float dot = red[0] + red[1] + red[2] + red[3];
  float sg = 1.f / (1.f + __expf(-(dot + bg2[0])));
  size_t base = (size_t)r * 512;
  out[base + t] = attn[base + t] * sg + prev[base + t] * (1.f - sg);
  out[base + t + 256] = attn[base + t + 256] * sg + prev[base + t + 256] * (1.f - sg);
}

// ---------------------------------------------------------------------------
extern "C" void kernel_launch(void* const* d_in, const int* in_sizes, int n_in,
                              void* d_out, int out_size, void* d_ws, size_t ws_size,
                              hipStream_t stream) {
  const float* q    = (const float*)d_in[0];
  const float* prev = (const float*)d_in[1];
  const float* Wq   = (const float*)d_in[2];
  const float* bq   = (const float*)d_in[3];
  const float* Wk   = (const float*)d_in[4];
  const float* bk   = (const float*)d_in[5];
  const float* Wv   = (const float*)d_in[6];
  const float* bv   = (const float*)d_in[7];
  const float* Wg1  = (const float*)d_in[8];
  const float* bg1  = (const float*)d_in[9];
  const float* Wg2  = (const float*)d_in[10];
  const float* bg2  = (const float*)d_in[11];
  const float* dk   = (const float*)d_in[12];
  const float* dv   = (const float*)d_in[13];
  float* out = (float*)d_out;

  char* ws = (char*)d_ws;
  u16*   kfr  = (u16*)(ws);                  // 33,554,432 B (fragment-ordered K)
  u16*   vt   = (u16*)(ws + 33554432);       // 33,554,432 B
  float* racc = (float*)(ws + 67108864);     // 2 MB
  float* lacc = (float*)(ws + 69206016);     // 4 KB (contiguous after racc)
  float* cqv  = (float*)(ws + 69210112);     // 4 KB
  u16*   q2   = (u16*)(ws + 69214208);       // 1 MB
  float* q1   = (float*)(ws + 70262784);     // 2 MB (reused as h)
  float* attn = (float*)(ws + 72359936);     // 2 MB   -> total 74,457,088 B
  float* h    = q1;

  prep_kfrag<<<1024, 256, 0, stream>>>(dk, kfr);
  prep_vt<<<dim3(512, 8), 256, 0, stream>>>(dv, vt);
  // q1 = (q @ Wq^T + bq) * D^-0.5
  gemm64<true, false, false, false, false><<<dim3(8, 16), 256, 0, stream>>>(
      q, nullptr, Wq, bq, nullptr, 0.044194173824159216f, q1, 1024, 512, 512);
  cq_kernel<<<1024, 64, 0, stream>>>(q1, bk, cqv);
  // Q2 = (q1 @ Wk) * 2   (bf16)
  gemm64<false, false, false, true, false><<<dim3(8, 16), 256, 0, stream>>>(
      q1, nullptr, Wk, nullptr, nullptr, 2.0f, q2, 1024, 512, 512);
  hipMemsetAsync(racc, 0, 2097152 + 4096, stream);  // racc + lacc
  flash<<<256, 512, 0, stream>>>(kfr, vt, q2, cqv, racc, lacc);
  // attn = (racc/l) @ Wv^T + bv
  gemm64<true, false, false, false, true><<<dim3(8, 16), 256, 0, stream>>>(
      racc, nullptr, Wv, bv, lacc, 1.0f, attn, 1024, 512, 512);
  // h = relu([attn|prev] @ Wg1^T + bg1)
  gemm64<true, true, true, false, false><<<dim3(8, 16), 256, 0, stream>>>(
      attn, prev, Wg1, bg1, nullptr, 1.0f, h, 1024, 512, 1024);
  finalize<<<1024, 256, 0, stream>>>(h, attn, prev, Wg2, bg2, out);
}